// Round 3
// baseline (679.900 us; speedup 1.0000x reference)
//
#include <hip/hip_runtime.h>
#include <math.h>

#define SMOOTHING 0.1f
#define EPSILON_F 1e-8f
#define ROWS_PER_BLOCK 4

// Combine two online-softmax states (m,s) <- (m,s) ⊕ (mo,so)
__device__ __forceinline__ void osm_combine(float& m, float& s, float mo, float so) {
    float nm = fmaxf(m, mo);
    s = s * __expf(m - nm) + so * __expf(mo - nm);
    m = nm;
}

// Chunked online-softmax update over one float4 + weighted-dot accumulation.
// Loop-carried chain: fmax -> sub -> exp -> fma (per 4 elements).
__device__ __forceinline__ void osm_upd4(float& m, float& s, float& wd,
                                         float4 v, float4 w) {
    float cm = fmaxf(fmaxf(v.x, v.y), fmaxf(v.z, v.w));
    float nm = fmaxf(m, cm);
    float e  = __expf(m - nm);
    float e0 = __expf(v.x - nm);
    float e1 = __expf(v.y - nm);
    float e2 = __expf(v.z - nm);
    float e3 = __expf(v.w - nm);
    s = fmaf(s, e, (e0 + e1) + (e2 + e3));
    m = nm;
    wd = fmaf(w.x, v.x, fmaf(w.y, v.y, fmaf(w.z, v.z, fmaf(w.w, v.w, wd))));
}

// 4 rows per 256-thread block: each weight float4 is loaded once and applied
// to 4 logits rows (4x less weight traffic through L2/L1). 5 independent
// float4 loads per thread-iteration keep bytes in flight; 4 independent
// online-softmax chains per thread.
__global__ __launch_bounds__(256) void Seq2SeqLoss_row_kernel(
    const float* __restrict__ logits,
    const int*   __restrict__ gold,
    const int*   __restrict__ mask,
    const float* __restrict__ weight,
    float*       __restrict__ row_loss,
    int C, int N)
{
    const int r0  = blockIdx.x * ROWS_PER_BLOCK;
    const int tid = threadIdx.x;
    const int C4  = C >> 2;   // C % 4 == 0

    // Clamp duplicate rows (only when N % ROWS_PER_BLOCK != 0) to a valid
    // pointer; their results are discarded at write time.
    const float4* __restrict__ x0 = (const float4*)(logits + (size_t)min(r0 + 0, N - 1) * (size_t)C);
    const float4* __restrict__ x1 = (const float4*)(logits + (size_t)min(r0 + 1, N - 1) * (size_t)C);
    const float4* __restrict__ x2 = (const float4*)(logits + (size_t)min(r0 + 2, N - 1) * (size_t)C);
    const float4* __restrict__ x3 = (const float4*)(logits + (size_t)min(r0 + 3, N - 1) * (size_t)C);
    const float4* __restrict__ w4 = (const float4*)weight;

    float m[ROWS_PER_BLOCK], s[ROWS_PER_BLOCK], wd[ROWS_PER_BLOCK];
    #pragma unroll
    for (int j = 0; j < ROWS_PER_BLOCK; ++j) { m[j] = -1e30f; s[j] = 0.f; wd[j] = 0.f; }
    float wsum = 0.f;

    for (int i = tid; i < C4; i += 256) {
        float4 w  = w4[i];
        float4 v0 = x0[i];
        float4 v1 = x1[i];
        float4 v2 = x2[i];
        float4 v3 = x3[i];
        wsum += (w.x + w.y) + (w.z + w.w);
        osm_upd4(m[0], s[0], wd[0], v0, w);
        osm_upd4(m[1], s[1], wd[1], v1, w);
        osm_upd4(m[2], s[2], wd[2], v2, w);
        osm_upd4(m[3], s[3], wd[3], v3, w);
    }

    // wave(64)-level reduce: wsum + 4x (M,S,wd)
    #pragma unroll
    for (int off = 32; off >= 1; off >>= 1) {
        wsum += __shfl_down(wsum, off);
        #pragma unroll
        for (int j = 0; j < ROWS_PER_BLOCK; ++j) {
            float Mo = __shfl_down(m[j], off);
            float So = __shfl_down(s[j], off);
            wd[j]   += __shfl_down(wd[j], off);
            osm_combine(m[j], s[j], Mo, So);
        }
    }

    // cross-wave (4 waves) via LDS
    __shared__ float shM[4][ROWS_PER_BLOCK], shS[4][ROWS_PER_BLOCK],
                     shWD[4][ROWS_PER_BLOCK], shWS[4];
    const int wave = tid >> 6;
    if ((tid & 63) == 0) {
        #pragma unroll
        for (int j = 0; j < ROWS_PER_BLOCK; ++j) {
            shM[wave][j] = m[j]; shS[wave][j] = s[j]; shWD[wave][j] = wd[j];
        }
        shWS[wave] = wsum;
    }
    __syncthreads();

    if (tid == 0) {
        #pragma unroll
        for (int w = 1; w < 4; ++w) {
            wsum += shWS[w];
            #pragma unroll
            for (int j = 0; j < ROWS_PER_BLOCK; ++j) {
                osm_combine(m[j], s[j], shM[w][j], shS[w][j]);
                wd[j] += shWD[w][j];
            }
        }

        const float uniform    = SMOOTHING / (float)(C - 1);
        const float confidence = 1.0f - SMOOTHING;

        #pragma unroll
        for (int j = 0; j < ROWS_PER_BLOCK; ++j) {
            int row = r0 + j;
            if (row < N) {
                float logZ = m[j] + logf(s[j]);
                int   g  = gold[row];
                float xg = logits[(size_t)row * (size_t)C + g];
                float wg = weight[g];
                float total    = logZ * wsum - wd[j];   // sum_c w_c * (logZ - x_c)
                float gold_nll = logZ - xg;
                float loss = uniform * total + (confidence - uniform) * wg * gold_nll;
                loss *= (mask[row] != 0) ? 1.0f : 0.0f;
                row_loss[row] = loss;
            }
        }
    }
}

// Single-block deterministic finalize: out = sum(row_loss) / (sum(mask) + eps)
__global__ __launch_bounds__(256) void Seq2SeqLoss_finalize_kernel(
    const float* __restrict__ row_loss,
    const int*   __restrict__ mask,
    float*       __restrict__ out,
    int N)
{
    const int tid = threadIdx.x;
    float acc = 0.f, cnt = 0.f;
    for (int i = tid; i < N; i += 256) {
        acc += row_loss[i];
        cnt += (mask[i] != 0) ? 1.0f : 0.0f;
    }
    #pragma unroll
    for (int off = 32; off >= 1; off >>= 1) {
        acc += __shfl_down(acc, off);
        cnt += __shfl_down(cnt, off);
    }
    __shared__ float shA[4], shC[4];
    const int wave = tid >> 6;
    if ((tid & 63) == 0) { shA[wave] = acc; shC[wave] = cnt; }
    __syncthreads();
    if (tid == 0) {
        #pragma unroll
        for (int w = 1; w < 4; ++w) { acc += shA[w]; cnt += shC[w]; }
        out[0] = acc / (cnt + EPSILON_F);
    }
}

extern "C" void kernel_launch(void* const* d_in, const int* in_sizes, int n_in,
                              void* d_out, int out_size, void* d_ws, size_t ws_size,
                              hipStream_t stream) {
    const float* logits = (const float*)d_in[0];   // [B,S,C] fp32
    const int*   gold   = (const int*)d_in[1];     // [B,S]   (int64 in ref -> int32 here)
    const int*   mask   = (const int*)d_in[2];     // [B,S]   (bool in ref -> int32 here)
    const float* weight = (const float*)d_in[3];   // [C]     fp32

    const int N = in_sizes[1];   // B*S = 4096 rows
    const int C = in_sizes[3];   // 32000 classes

    float* row_loss = (float*)d_ws;  // N floats = 16 KB scratch

    const int nblocks = (N + ROWS_PER_BLOCK - 1) / ROWS_PER_BLOCK;
    Seq2SeqLoss_row_kernel<<<nblocks, 256, 0, stream>>>(logits, gold, mask, weight,
                                                        row_loss, C, N);
    Seq2SeqLoss_finalize_kernel<<<1, 256, 0, stream>>>(row_loss, mask, (float*)d_out, N);
}